// Round 3
// baseline (272.707 us; speedup 1.0000x reference)
//
#include <hip/hip_runtime.h>
#include <hip/hip_cooperative_groups.h>

namespace cg = cooperative_groups;

#define NN 1024

// One cooperative kernel, 512 blocks x 256 threads, 3 grid syncs.
// Stage 1: layer1 pair-sum (c1 tile computed on the fly from x)   -> out1
// Stage 2: layer2 a2,c2 = out1 @ W2 + b2                          -> a2,c2
// Stage 3: layer2 pair-sum + per-block partial column sums        -> out2, partials
// Stage 4 (blocks 0..7): reduce partials -> S; separable layer 3  -> out
__global__ __launch_bounds__(256) void fused_net(
    const float* __restrict__ x,  const float* __restrict__ W1, const float* __restrict__ b1,
    const float* __restrict__ W2, const float* __restrict__ b2,
    const float* __restrict__ W3, const float* __restrict__ b3,
    float* __restrict__ out,
    float* __restrict__ out1, float* __restrict__ a2g, float* __restrict__ c2g,
    float* __restrict__ out2, float* __restrict__ partials)
{
    cg::grid_group grid = cg::this_grid();
    __shared__ float cbuf[8192];      // 32 KB tile buffer (union: c1-tiles / c2-tiles)
    __shared__ float pcol[4][64];
    __shared__ float sS[4];

    const int tid  = threadIdx.x;
    const int wave = tid >> 6, lane = tid & 63;
    const int blk  = blockIdx.x;

    // ---------------- Stage 1: pair-sum F=32 (relu), c1 on the fly ----------------
    {
        int i  = blk * 4 + wave;            // global row 0..2047
        int b  = i >> 10;
        int il = i & 1023;
        int js = lane >> 5, f = lane & 31;
        const float* xb = x + b * (NN * 3);
        float xi0 = xb[il*3+0], xi1 = xb[il*3+1], xi2 = xb[il*3+2];
        float a     = xi0*W1[0*32+f] + xi1*W1[1*32+f] + xi2*W1[2*32+f];
        float cself = xi0*W1[3*32+f] + xi1*W1[4*32+f] + xi2*W1[5*32+f] + b1[f];
        float acc = 0.f;
        int f2 = tid & 31, r0 = tid >> 5;   // c-tile compute assignment
        float w3f = W1[3*32+f2], w4f = W1[4*32+f2], w5f = W1[5*32+f2], bf = b1[f2];
        for (int tile = 0; tile < NN; tile += 256) {
            #pragma unroll 4
            for (int k = 0; k < 32; ++k) {
                int r = tile + r0 + k*8;
                float y0 = xb[r*3+0], y1 = xb[r*3+1], y2 = xb[r*3+2];
                cbuf[(r0 + k*8)*32 + f2] = y0*w3f + y1*w4f + y2*w5f + bf;
            }
            __syncthreads();
            #pragma unroll 8
            for (int jj = js; jj < 256; jj += 2)
                acc += fmaxf(a + cbuf[jj*32 + f], 0.f);
            __syncthreads();
        }
        acc += __shfl_xor(acc, 32);
        float res = (acc - fmaxf(a + cself, 0.f)) * (1.0f/1023.0f);
        if (js == 0) out1[i*32 + f] = res;
    }
    grid.sync();

    // ---------------- Stage 2: a2,c2 (one output per thread) ----------------
    {
        int t = blk * 256 + tid;            // 0..131071
        int i = t >> 6, f = t & 63;
        const float* hr = out1 + i * 32;
        float a = 0.f, c = b2[f];
        #pragma unroll
        for (int d = 0; d < 32; ++d) {
            float hv = hr[d];
            a += hv * W2[d*64 + f];
            c += hv * W2[(32 + d)*64 + f];
        }
        a2g[t] = a;
        c2g[t] = c;
    }
    grid.sync();

    // ---------------- Stage 3: pair-sum F=64 (relu) + partial colsum ----------------
    {
        int i = blk * 4 + wave;
        int b = i >> 10;
        const float* cb = c2g + b * (NN * 64);
        float a = a2g[i*64 + lane];
        float acc = 0.f;
        for (int tile = 0; tile < NN; tile += 128) {
            const float4* src = (const float4*)(cb + tile * 64);
            float4* dst = (float4*)cbuf;
            for (int k = tid; k < 2048; k += 256) dst[k] = src[k];
            __syncthreads();
            #pragma unroll 8
            for (int jj = 0; jj < 128; ++jj)
                acc += fmaxf(a + cbuf[jj*64 + lane], 0.f);
            __syncthreads();
        }
        float res = (acc - fmaxf(a + c2g[i*64 + lane], 0.f)) * (1.0f/1023.0f);
        out2[i*64 + lane] = res;
        pcol[wave][lane] = res;
        __syncthreads();
        if (tid < 64)
            partials[blk*64 + tid] = pcol[0][tid] + pcol[1][tid] + pcol[2][tid] + pcol[3][tid];
    }
    grid.sync();

    // ---------------- Stage 4: reduce partials -> S; separable final layer ----------------
    if (blk < 8) {
        int b = blk >> 2;                   // batch
        {
            int col = tid & 63, q = tid >> 6;
            float s = 0.f;
            const float* pb = partials + b * 256 * 64;
            #pragma unroll 8
            for (int k = q*64; k < q*64 + 64; ++k) s += pb[k*64 + col];
            pcol[q][col] = s;
        }
        __syncthreads();
        if (wave < 3) {
            float cs = pcol[0][lane] + pcol[1][lane] + pcol[2][lane] + pcol[3][lane];
            float p = cs * W3[(64 + lane)*3 + wave];
            #pragma unroll
            for (int off = 32; off; off >>= 1) p += __shfl_xor(p, off);
            if (lane == 0) sS[wave] = p;
        }
        __syncthreads();
        int t = blk * 256 + tid;            // global row 0..2047
        const float* row = out2 + t * 64;
        float r0 = 0, r1 = 0, r2 = 0, q0 = 0, q1 = 0, q2 = 0;
        #pragma unroll
        for (int d = 0; d < 64; ++d) {
            float v = row[d];
            r0 += v * W3[d*3+0];       r1 += v * W3[d*3+1];       r2 += v * W3[d*3+2];
            q0 += v * W3[(64+d)*3+0];  q1 += v * W3[(64+d)*3+1];  q2 += v * W3[(64+d)*3+2];
        }
        float* o = out + t * 3;
        o[0] = r0 + b3[0] + (sS[0] - q0) * (1.0f/1023.0f);
        o[1] = r1 + b3[1] + (sS[1] - q1) * (1.0f/1023.0f);
        o[2] = r2 + b3[2] + (sS[2] - q2) * (1.0f/1023.0f);
    }
}

extern "C" void kernel_launch(void* const* d_in, const int* in_sizes, int n_in,
                              void* d_out, int out_size, void* d_ws, size_t ws_size,
                              hipStream_t stream) {
    const float* x  = (const float*)d_in[0];
    const float* W1 = (const float*)d_in[1];
    const float* b1 = (const float*)d_in[2];
    const float* W2 = (const float*)d_in[3];
    const float* b2 = (const float*)d_in[4];
    const float* W3 = (const float*)d_in[5];
    const float* b3 = (const float*)d_in[6];
    float* out = (float*)d_out;

    float* ws = (float*)d_ws;
    float* out1     = ws;                   // 2048*32
    float* a2g      = out1 + 2048*32;       // 2048*64
    float* c2g      = a2g  + 2048*64;       // 2048*64
    float* out2     = c2g  + 2048*64;       // 2048*64
    float* partials = out2 + 2048*64;       // 512*64

    void* args[] = { (void*)&x, (void*)&W1, (void*)&b1, (void*)&W2, (void*)&b2,
                     (void*)&W3, (void*)&b3, (void*)&out,
                     (void*)&out1, (void*)&a2g, (void*)&c2g, (void*)&out2, (void*)&partials };
    hipLaunchCooperativeKernel((void*)fused_net, dim3(512), dim3(256), args, 0, stream);
}

// Round 4
// 114.499 us; speedup vs baseline: 2.3817x; 2.3817x over previous
//
#include <hip/hip_runtime.h>

#define NN 1024

// ---------------- K1: fused ac1 + pair32(relu) + ac2 ----------------
// 512 blocks x 256. Each wave owns one row i = blk*4+wave.
// Phase A: c1-tiles computed on the fly from x into LDS; pair-sum F=32.
// Phase B: out1 row (32 vals) -> LDS; each lane computes a2,c2 (f=lane).
__global__ __launch_bounds__(256) void k1_pair32_ac2(
    const float* __restrict__ x,  const float* __restrict__ W1, const float* __restrict__ b1,
    const float* __restrict__ W2, const float* __restrict__ b2,
    float* __restrict__ a2g, float* __restrict__ c2g)
{
    __shared__ float cbuf[8192];        // 32 KB c1 tile (256 rows x 32)
    __shared__ float rowbuf[4][32];     // out1 rows, one per wave

    const int tid  = threadIdx.x;
    const int wave = tid >> 6, lane = tid & 63;
    const int blk  = blockIdx.x;

    const int i  = blk * 4 + wave;      // 0..2047
    const int b  = i >> 10;
    const int il = i & 1023;
    const int js = lane >> 5, f = lane & 31;
    const float* xb = x + b * (NN * 3);

    const float xi0 = xb[il*3+0], xi1 = xb[il*3+1], xi2 = xb[il*3+2];
    const float a     = xi0*W1[0*32+f] + xi1*W1[1*32+f] + xi2*W1[2*32+f];
    const float cself = xi0*W1[3*32+f] + xi1*W1[4*32+f] + xi2*W1[5*32+f] + b1[f];

    float acc = 0.f;
    const int f2 = tid & 31, r0 = tid >> 5;   // c-tile compute assignment
    const float w3f = W1[3*32+f2], w4f = W1[4*32+f2], w5f = W1[5*32+f2], bf = b1[f2];
    for (int tile = 0; tile < NN; tile += 256) {
        #pragma unroll 4
        for (int k = 0; k < 32; ++k) {
            int r = tile + r0 + k*8;
            float y0 = xb[r*3+0], y1 = xb[r*3+1], y2 = xb[r*3+2];
            cbuf[(r0 + k*8)*32 + f2] = y0*w3f + y1*w4f + y2*w5f + bf;
        }
        __syncthreads();
        #pragma unroll 8
        for (int jj = js; jj < 256; jj += 2)
            acc += fmaxf(a + cbuf[jj*32 + f], 0.f);
        __syncthreads();
    }
    acc += __shfl_xor(acc, 32);
    float res = (acc - fmaxf(a + cself, 0.f)) * (1.0f/1023.0f);
    if (js == 0) rowbuf[wave][f] = res;
    __syncthreads();

    // ---- ac2 epilogue: h-row (32) @ W2 (64x64) + b2 ----
    float av = 0.f, cv = b2[lane];
    #pragma unroll
    for (int d = 0; d < 32; ++d) {
        float hv = rowbuf[wave][d];     // LDS broadcast, conflict-free
        av += hv * W2[d*64 + lane];
        cv += hv * W2[(32 + d)*64 + lane];
    }
    a2g[i*64 + lane] = av;
    c2g[i*64 + lane] = cv;
}

// ---------------- K2: pair-sum F=64 (relu) + per-block partial colsum ----------------
__global__ __launch_bounds__(256) void k2_pair64(
    const float* __restrict__ a2g, const float* __restrict__ c2g,
    float* __restrict__ out2, float* __restrict__ partials)
{
    __shared__ float cbuf[8192];        // 32 KB (128 rows x 64)
    __shared__ float pcol[4][64];

    const int tid  = threadIdx.x;
    const int wave = tid >> 6, lane = tid & 63;
    const int blk  = blockIdx.x;

    const int i = blk * 4 + wave;
    const int b = i >> 10;
    const float* cb = c2g + b * (NN * 64);
    const float a = a2g[i*64 + lane];
    float acc = 0.f;
    for (int tile = 0; tile < NN; tile += 128) {
        const float4* src = (const float4*)(cb + tile * 64);
        float4* dst = (float4*)cbuf;
        for (int k = tid; k < 2048; k += 256) dst[k] = src[k];
        __syncthreads();
        #pragma unroll 8
        for (int jj = 0; jj < 128; ++jj)
            acc += fmaxf(a + cbuf[jj*64 + lane], 0.f);
        __syncthreads();
    }
    float res = (acc - fmaxf(a + cb[(i & 1023)*64 + lane], 0.f)) * (1.0f/1023.0f);
    out2[i*64 + lane] = res;
    pcol[wave][lane] = res;
    __syncthreads();
    if (tid < 64)
        partials[blk*64 + tid] = pcol[0][tid] + pcol[1][tid] + pcol[2][tid] + pcol[3][tid];
}

// ---------------- K3: reduce partials -> S; separable final layer ----------------
// 8 blocks x 256; blocks 0..3 batch 0 rows, 4..7 batch 1 rows.
__global__ __launch_bounds__(256) void k3_final(
    const float* __restrict__ out2, const float* __restrict__ partials,
    const float* __restrict__ W3, const float* __restrict__ b3,
    float* __restrict__ out)
{
    __shared__ float pcol[4][64];
    __shared__ float sS[4];

    const int tid  = threadIdx.x;
    const int wave = tid >> 6, lane = tid & 63;
    const int blk  = blockIdx.x;
    const int b = blk >> 2;             // batch

    {
        int col = tid & 63, q = tid >> 6;
        float s = 0.f;
        const float* pb = partials + b * 256 * 64;
        #pragma unroll 8
        for (int k = q*64; k < q*64 + 64; ++k) s += pb[k*64 + col];
        pcol[q][col] = s;
    }
    __syncthreads();
    if (wave < 3) {
        float cs = pcol[0][lane] + pcol[1][lane] + pcol[2][lane] + pcol[3][lane];
        float p = cs * W3[(64 + lane)*3 + wave];
        #pragma unroll
        for (int off = 32; off; off >>= 1) p += __shfl_xor(p, off);
        if (lane == 0) sS[wave] = p;
    }
    __syncthreads();

    const int t = blk * 256 + tid;      // global row 0..2047
    const float* row = out2 + t * 64;
    float r0 = 0, r1 = 0, r2 = 0, q0 = 0, q1 = 0, q2 = 0;
    #pragma unroll
    for (int d = 0; d < 64; ++d) {
        float v = row[d];
        r0 += v * W3[d*3+0];       r1 += v * W3[d*3+1];       r2 += v * W3[d*3+2];
        q0 += v * W3[(64+d)*3+0];  q1 += v * W3[(64+d)*3+1];  q2 += v * W3[(64+d)*3+2];
    }
    float* o = out + t * 3;
    o[0] = r0 + b3[0] + (sS[0] - q0) * (1.0f/1023.0f);
    o[1] = r1 + b3[1] + (sS[1] - q1) * (1.0f/1023.0f);
    o[2] = r2 + b3[2] + (sS[2] - q2) * (1.0f/1023.0f);
}

extern "C" void kernel_launch(void* const* d_in, const int* in_sizes, int n_in,
                              void* d_out, int out_size, void* d_ws, size_t ws_size,
                              hipStream_t stream) {
    const float* x  = (const float*)d_in[0];
    const float* W1 = (const float*)d_in[1];
    const float* b1 = (const float*)d_in[2];
    const float* W2 = (const float*)d_in[3];
    const float* b2 = (const float*)d_in[4];
    const float* W3 = (const float*)d_in[5];
    const float* b3 = (const float*)d_in[6];
    float* out = (float*)d_out;

    float* ws = (float*)d_ws;
    float* a2g      = ws;                   // 2048*64
    float* c2g      = a2g  + 2048*64;       // 2048*64
    float* out2     = c2g  + 2048*64;       // 2048*64
    float* partials = out2 + 2048*64;       // 512*64

    k1_pair32_ac2<<<512, 256, 0, stream>>>(x, W1, b1, W2, b2, a2g, c2g);
    k2_pair64<<<512, 256, 0, stream>>>(a2g, c2g, out2, partials);
    k3_final<<<8, 256, 0, stream>>>(out2, partials, W3, b3, out);
}

// Round 5
// 105.254 us; speedup vs baseline: 2.5909x; 1.0878x over previous
//
#include <hip/hip_runtime.h>

#define NN 1024

// ---------------- K1: fused ac1 + pair32(relu) + ac2 ----------------
// 512 blocks x 256. Each wave owns one row i = blk*4+wave.
// Phase A: c1-tiles computed on the fly from x into LDS; pair-sum F=32.
// Phase B: out1 row (32 vals) -> LDS; each lane computes a2,c2 (f=lane).
__global__ __launch_bounds__(256) void k1_pair32_ac2(
    const float* __restrict__ x,  const float* __restrict__ W1, const float* __restrict__ b1,
    const float* __restrict__ W2, const float* __restrict__ b2,
    float* __restrict__ a2g, float* __restrict__ c2g)
{
    __shared__ float cbuf[8192];        // 32 KB c1 tile (256 rows x 32)
    __shared__ float rowbuf[4][32];     // out1 rows, one per wave

    const int tid  = threadIdx.x;
    const int wave = tid >> 6, lane = tid & 63;
    const int blk  = blockIdx.x;

    const int i  = blk * 4 + wave;      // 0..2047
    const int b  = i >> 10;
    const int il = i & 1023;
    const int js = lane >> 5, f = lane & 31;
    const float* xb = x + b * (NN * 3);

    const float xi0 = xb[il*3+0], xi1 = xb[il*3+1], xi2 = xb[il*3+2];
    const float a     = xi0*W1[0*32+f] + xi1*W1[1*32+f] + xi2*W1[2*32+f];
    const float cself = xi0*W1[3*32+f] + xi1*W1[4*32+f] + xi2*W1[5*32+f] + b1[f];

    float acc = 0.f;
    const int f2 = tid & 31, r0 = tid >> 5;   // c-tile compute assignment
    const float w3f = W1[3*32+f2], w4f = W1[4*32+f2], w5f = W1[5*32+f2], bf = b1[f2];
    for (int tile = 0; tile < NN; tile += 256) {
        #pragma unroll 4
        for (int k = 0; k < 32; ++k) {
            int r = tile + r0 + k*8;
            float y0 = xb[r*3+0], y1 = xb[r*3+1], y2 = xb[r*3+2];
            cbuf[(r0 + k*8)*32 + f2] = y0*w3f + y1*w4f + y2*w5f + bf;
        }
        __syncthreads();
        #pragma unroll 8
        for (int jj = js; jj < 256; jj += 2)
            acc += fmaxf(a + cbuf[jj*32 + f], 0.f);
        __syncthreads();
    }
    acc += __shfl_xor(acc, 32);
    float res = (acc - fmaxf(a + cself, 0.f)) * (1.0f/1023.0f);
    if (js == 0) rowbuf[wave][f] = res;
    __syncthreads();

    // ---- ac2 epilogue: h-row (32) @ W2 (64x64) + b2 ----
    float av = 0.f, cv = b2[lane];
    #pragma unroll
    for (int d = 0; d < 32; ++d) {
        float hv = rowbuf[wave][d];     // LDS broadcast, conflict-free
        av += hv * W2[d*64 + lane];
        cv += hv * W2[(32 + d)*64 + lane];
    }
    a2g[i*64 + lane] = av;
    c2g[i*64 + lane] = cv;
}

// ---------------- K2: pair-sum F=64 (relu) + fused final projection ----------------
// 512 blocks x 256. Block owns rows i0..i0+3.
// Wave w: rowpair rw=w>>1 (rows i0+2rw, i0+2rw+1), j-half jh=w&1.
// After j-loop, halves combined via LDS; wave w finalizes row i0+w, projects
// through W3 (butterfly reduce) and writes y to out; per-block S-partial saved.
__global__ __launch_bounds__(256) void k2_pair64_final(
    const float* __restrict__ a2g, const float* __restrict__ c2g,
    const float* __restrict__ W3, const float* __restrict__ b3,
    float* __restrict__ out, float* __restrict__ partials)
{
    __shared__ float cbuf[8192];        // 32 KB (128 rows x 64)
    __shared__ float pacc[4][2][64];
    __shared__ float qpart[4][3];

    const int tid  = threadIdx.x;
    const int wave = tid >> 6, lane = tid & 63;
    const int blk  = blockIdx.x;

    const int i0 = blk * 4;
    const int b  = blk >> 8;            // batch
    const int rw = wave >> 1, jh = wave & 1;
    const int rowA = i0 + 2*rw, rowB = rowA + 1;

    const float* cb = c2g + b * (NN * 64);
    const float a0 = a2g[rowA*64 + lane];
    const float a1 = a2g[rowB*64 + lane];
    float acc0 = 0.f, acc1 = 0.f;

    for (int tile = 0; tile < NN; tile += 128) {
        const float4* src = (const float4*)(cb + tile * 64);
        float4* dst = (float4*)cbuf;
        for (int k = tid; k < 2048; k += 256) dst[k] = src[k];
        __syncthreads();
        // wave covers jj = jh, jh+2, ..., 126+jh  (64 of the 128 rows)
        #pragma unroll 8
        for (int k = 0; k < 64; ++k) {
            float c = cbuf[(2*k + jh)*64 + lane];
            acc0 += fmaxf(a0 + c, 0.f);
            acc1 += fmaxf(a1 + c, 0.f);
        }
        __syncthreads();
    }
    pacc[wave][0][lane] = acc0;
    pacc[wave][1][lane] = acc1;
    __syncthreads();

    // ---- finalize: wave w owns row i0+w ----
    const int i = i0 + wave;
    const int wpair = 2*(wave >> 1);    // waves that computed this rowpair
    float accf = pacc[wpair][wave & 1][lane] + pacc[wpair + 1][wave & 1][lane];
    float aself = a2g[i*64 + lane];
    float self  = fmaxf(aself + cb[(i & 1023)*64 + lane], 0.f);
    float res = (accf - self) * (1.0f/1023.0f);

    // per-lane W3 rows: top = W3[lane][t], bottom = W3[64+lane][t]
    float wt0 = W3[lane*3+0], wt1 = W3[lane*3+1], wt2 = W3[lane*3+2];
    float wb0 = W3[(64+lane)*3+0], wb1 = W3[(64+lane)*3+1], wb2 = W3[(64+lane)*3+2];
    float y0 = res * (wt0 - wb0*(1.0f/1023.0f));
    float y1 = res * (wt1 - wb1*(1.0f/1023.0f));
    float y2 = res * (wt2 - wb2*(1.0f/1023.0f));
    float q0 = res * wb0, q1 = res * wb1, q2 = res * wb2;
    #pragma unroll
    for (int off = 32; off; off >>= 1) {
        y0 += __shfl_xor(y0, off);  y1 += __shfl_xor(y1, off);  y2 += __shfl_xor(y2, off);
        q0 += __shfl_xor(q0, off);  q1 += __shfl_xor(q1, off);  q2 += __shfl_xor(q2, off);
    }
    if (lane == 0) {
        out[i*3+0] = y0 + b3[0];
        out[i*3+1] = y1 + b3[1];
        out[i*3+2] = y2 + b3[2];
        qpart[wave][0] = q0;  qpart[wave][1] = q1;  qpart[wave][2] = q2;
    }
    __syncthreads();
    if (tid < 3)
        partials[blk*3 + tid] = qpart[0][tid] + qpart[1][tid] + qpart[2][tid] + qpart[3][tid];
}

// ---------------- K3: reduce partials -> S; broadcast add ----------------
// 8 blocks x 256; block blk: batch b=blk>>2, rows (blk&3)*256 + tid of that batch.
__global__ __launch_bounds__(256) void k3_final(
    const float* __restrict__ partials, float* __restrict__ out)
{
    __shared__ float red[4][3];

    const int tid  = threadIdx.x;
    const int wave = tid >> 6, lane = tid & 63;
    const int blk  = blockIdx.x;
    const int b = blk >> 2;

    // 256 threads <-> 256 blocks of this batch
    const float* pb = partials + b * 256 * 3;
    float s0 = pb[tid*3+0], s1 = pb[tid*3+1], s2 = pb[tid*3+2];
    #pragma unroll
    for (int off = 32; off; off >>= 1) {
        s0 += __shfl_xor(s0, off);  s1 += __shfl_xor(s1, off);  s2 += __shfl_xor(s2, off);
    }
    if (lane == 0) { red[wave][0] = s0; red[wave][1] = s1; red[wave][2] = s2; }
    __syncthreads();
    float S0 = (red[0][0]+red[1][0]+red[2][0]+red[3][0]) * (1.0f/1023.0f);
    float S1 = (red[0][1]+red[1][1]+red[2][1]+red[3][1]) * (1.0f/1023.0f);
    float S2 = (red[0][2]+red[1][2]+red[2][2]+red[3][2]) * (1.0f/1023.0f);

    const int i = b * NN + (blk & 3) * 256 + tid;   // global row
    out[i*3+0] += S0;
    out[i*3+1] += S1;
    out[i*3+2] += S2;
}

extern "C" void kernel_launch(void* const* d_in, const int* in_sizes, int n_in,
                              void* d_out, int out_size, void* d_ws, size_t ws_size,
                              hipStream_t stream) {
    const float* x  = (const float*)d_in[0];
    const float* W1 = (const float*)d_in[1];
    const float* b1 = (const float*)d_in[2];
    const float* W2 = (const float*)d_in[3];
    const float* b2 = (const float*)d_in[4];
    const float* W3 = (const float*)d_in[5];
    const float* b3 = (const float*)d_in[6];
    float* out = (float*)d_out;

    float* ws = (float*)d_ws;
    float* a2g      = ws;                   // 2048*64
    float* c2g      = a2g + 2048*64;        // 2048*64
    float* partials = c2g + 2048*64;        // 512*3

    k1_pair32_ac2<<<512, 256, 0, stream>>>(x, W1, b1, W2, b2, a2g, c2g);
    k2_pair64_final<<<512, 256, 0, stream>>>(a2g, c2g, W3, b3, out, partials);
    k3_final<<<8, 256, 0, stream>>>(partials, out);
}